// Round 15
// baseline (34.266 us; speedup 1.0000x reference)
//
#include <hip/hip_runtime.h>
#include <math.h>

typedef unsigned short ushort;
typedef unsigned int uint;
typedef unsigned char uchar;

#define B 4
#define C 64
#define H 64
#define W 64
#define HW 4096
#define NEG 256
#define NGRP 16
#define PXB 64                   // pixels per k_main block
#define NBLK (B * HW / PXB)      // 256 blocks = 1 per CU

#define QS 7.49f
#define INVQS2 (1.0f / (QS * QS))
#define RGBNORM5 0.0186243f      // 1/(31*sqrt(3))

// ---------------- ws layout (float units) ----------------
#define OFF_Z2A    0
#define OFF_Z2B    (OFF_Z2A + B*HW*4)
#define OFF_N1MAP  (OFF_Z2B + B*HW*4)
#define OFF_IMGU16 (OFF_N1MAP + B*HW)
#define OFF_PART2  (OFF_IMGU16 + HW/2)

__device__ __forceinline__ int nib(uint u, int j) {
    return ((int)(u << (28 - 4 * j))) >> 28;
}
__device__ __forceinline__ int dot8(uint a, uint b, int c) {
#if __has_builtin(__builtin_amdgcn_sdot8)
    return __builtin_amdgcn_sdot8((int)a, (int)b, c, false);
#else
#pragma unroll
    for (int j = 0; j < 8; ++j) c += nib(a, j) * nib(b, j);
    return c;
#endif
}

// Combined prep: blocks [0,256) transpose+quantize z2 -> split int4 columns (A/B);
// blocks [256,320) do n1map + RGB555 img table + zero partial2.
__global__ __launch_bounds__(256) void k_prep(const float* __restrict__ v2,
                                              const float* __restrict__ v1,
                                              const float* __restrict__ img,
                                              uchar* __restrict__ z2Ag,
                                              uchar* __restrict__ z2Bg,
                                              float* __restrict__ n1map,
                                              ushort* __restrict__ img_u16,
                                              float* __restrict__ partial2) {
    int t = threadIdx.x;
    if (blockIdx.x < 256) {
        __shared__ float tile[64][65];
        __shared__ float npart[4][64];
        __shared__ float ninv[64];
        int b  = blockIdx.x >> 6;
        int q0 = (blockIdx.x & 63) * 64;
        int qq = t & 63;
        int cg = t >> 6;
        const float* src = v2 + (size_t)b * C * HW;
        float acc = 0.f;
#pragma unroll
        for (int r = 0; r < 16; ++r) {
            int c = cg * 16 + r;
            float v = src[(size_t)c * HW + q0 + qq];
            tile[c][qq] = v;
            acc += v * v;
        }
        npart[cg][qq] = acc;
        __syncthreads();
        if (t < 64) {
            float s = npart[0][t] + npart[1][t] + npart[2][t] + npart[3][t];
            ninv[t] = QS / fmaxf(sqrtf(s), 1e-8f);
        }
        __syncthreads();
        int qw   = t >> 2;
        int quad = t & 3;
        int c0   = quad * 16;
        float inv = ninv[qw];
        uint u0 = 0, u1 = 0;
#pragma unroll
        for (int j = 0; j < 8; ++j) {
            int x0 = (int)rintf(tile[c0 + j][qw] * inv);
            int x1 = (int)rintf(tile[c0 + 8 + j][qw] * inv);
            u0 |= (uint)(x0 & 0xF) << (4 * j);
            u1 |= (uint)(x1 & 0xF) << (4 * j);
        }
        size_t col = (size_t)b * HW + q0 + qw;
        uint2 val = make_uint2(u0, u1);
        if (quad < 2) *(uint2*)(z2Ag + col * 16 + quad * 8)       = val;
        else          *(uint2*)(z2Bg + col * 16 + (quad - 2) * 8) = val;
    } else {
        int bid = blockIdx.x - 256;          // 0..63
        int b = bid >> 4;
        int q = (bid & 15) * 256 + t;
        partial2[bid * 256 + t] = 0.f;       // 64*256 == B*NGRP*NEG
        const float* src = v1 + (size_t)b * C * HW + q;
        float acc = 0.f;
#pragma unroll 8
        for (int c = 0; c < C; ++c) {
            float v = src[(size_t)c * HW];
            acc += v * v;
        }
        n1map[b * HW + q] = sqrtf(acc);
        if (b == 0) {
            uint r  = (uint)rintf(img[q] * 31.f);
            uint g  = (uint)rintf(img[HW + q] * 31.f);
            uint bl = (uint)rintf(img[2 * HW + q] * 31.f);
            img_u16[q] = (ushort)(r | (g << 5) | (bl << 10));
        }
    }
}

// Main: 256 blocks x 1024 threads (16 waves/CU). Whole-item z2 (128 KB, A/B split)
// + img in LDS. Phase-split per 8-px group for ILP: {qv,wv}x8 -> 16 LDS b128 loads
// -> 64 dot8s. Block-level pre-reduce, one atomic per k per block.
__global__ __launch_bounds__(1024, 4) void k_main(const float* __restrict__ v1,
                                                  const int* __restrict__ negh,
                                                  const int* __restrict__ negw,
                                                  const uint4* __restrict__ z2Ag,
                                                  const uint4* __restrict__ z2Bg,
                                                  const float* __restrict__ n1map,
                                                  const ushort* __restrict__ img_u16,
                                                  float* __restrict__ partial2) {
    __shared__ uint4 zA[HW];                // 64 KB: channels 0-31 per column
    __shared__ uint4 zB[HW];                // 64 KB: channels 32-63 per column
    __shared__ ushort imgu[HW];             // 8 KB RGB555
    __shared__ uint z1q[PXB][8];            // 2 KB int4-packed z1 columns
    __shared__ float redk[NEG];             // 1 KB per-k block reduction
    int b  = blockIdx.x >> 6;
    int p0 = (blockIdx.x & 63) * PXB;
    int t  = threadIdx.x;

    {   // stage whole-item z2 (A/B) + img table, fully coalesced
        const uint4* gA = z2Ag + (size_t)b * HW;
        const uint4* gB = z2Bg + (size_t)b * HW;
#pragma unroll
        for (int i = 0; i < 4; ++i) {
            zA[i * 1024 + t] = gA[i * 1024 + t];
            zB[i * 1024 + t] = gB[i * 1024 + t];
        }
        if (t < 512) ((uint4*)imgu)[t] = ((const uint4*)img_u16)[t];
        if (t < NEG) redk[t] = 0.f;
    }
    if (t < 512) {   // stage z1 columns, normalized xQS -> int4 packed (64 px x 8)
        int px = t >> 3;
        int ui = t & 7;
        const float* srcb = v1 + (size_t)b * C * HW + p0 + px;
        float inv = QS / fmaxf(n1map[b * HW + p0 + px], 1e-8f);
        uint u = 0;
#pragma unroll
        for (int j = 0; j < 8; ++j) {
            int x = (int)rintf(srcb[(size_t)(8 * ui + j) * HW] * inv);
            u |= (uint)(x & 0xF) << (4 * j);
        }
        z1q[px][ui] = u;
    }
    __syncthreads();

    const float inv_max_euc = 1.0f / sqrtf((float)((H - 1) * (H - 1) + (W - 1) * (W - 1)));
    int k       = t & 255;
    int quarter = t >> 8;                  // 0..3
    int pbase   = p0 + quarter * 16;
    const int* nh = negh + ((size_t)b * HW + pbase) * NEG + k;
    const int* nw = negw + ((size_t)b * HW + pbase) * NEG + k;

    float acc = 0.f;
#pragma unroll
    for (int j0 = 0; j0 < 16; j0 += 8) {
        // (i) idx loads, batched
        int ihv[8], iwv[8];
#pragma unroll
        for (int j = 0; j < 8; ++j) {
            ihv[j] = nh[(j0 + j) * NEG];
            iwv[j] = nw[(j0 + j) * NEG];
        }
        // (ii) qv + weight for all 8 px
        int   qvv[8];
        float wvv[8];
#pragma unroll
        for (int j = 0; j < 8; ++j) {
            int p  = pbase + j0 + j;
            int ih = ihv[j], iw = iwv[j];
            int qv = (ih << 6) + iw;
            float dh = (float)(p >> 6) - (float)ih;
            float dw = (float)(p & 63) - (float)iw;
            float euc = sqrtf(dh * dh + dw * dw) * inv_max_euc;
            uint up = imgu[p];
            uint uq = imgu[qv];
            int dr = (int)(up & 31u)         - (int)(uq & 31u);
            int dg = (int)((up >> 5) & 31u)  - (int)((uq >> 5) & 31u);
            int db = (int)((up >> 10) & 31u) - (int)((uq >> 10) & 31u);
            float rgb = sqrtf((float)(dr * dr + dg * dg + db * db)) * RGBNORM5;
            wvv[j] = (0.8f * euc + 0.2f * rgb) * INVQS2;
            qvv[j] = qv;
        }
        // (iii) issue all 16 LDS b128 gathers
        uint4 Av[8], Bv[8];
#pragma unroll
        for (int j = 0; j < 8; ++j) {
            Av[j] = zA[qvv[j]];
            Bv[j] = zB[qvv[j]];
        }
        // (iv) dots
#pragma unroll
        for (int j = 0; j < 8; ++j) {
            int px = quarter * 16 + j0 + j;
            const uint4* zc = (const uint4*)(&z1q[px][0]);   // uniform -> broadcast
            uint4 u0 = zc[0];
            uint4 u1 = zc[1];
            int di = 0;
            di = dot8(Av[j].x, u0.x, di);
            di = dot8(Av[j].y, u0.y, di);
            di = dot8(Av[j].z, u0.z, di);
            di = dot8(Av[j].w, u0.w, di);
            di = dot8(Bv[j].x, u1.x, di);
            di = dot8(Bv[j].y, u1.y, di);
            di = dot8(Bv[j].z, u1.z, di);
            di = dot8(Bv[j].w, u1.w, di);
            acc += fminf(fabsf((float)di * wvv[j]), 1.0f);
        }
    }
    // block-level pre-reduce over quarters, then one atomic per k
    atomicAdd(&redk[k], acc);     // LDS atomic, 4-way
    __syncthreads();
    if (t < NEG)
        atomicAdd(&partial2[((size_t)b * NGRP + ((blockIdx.x & 63) >> 2)) * NEG + t],
                  redk[t]);
}

// Merged stage-2 + final with shfl wave reductions.
__global__ __launch_bounds__(256) void k_reduce2f(const float* __restrict__ partial2,
                                                  const float* __restrict__ n1map,
                                                  float* __restrict__ out) {
    __shared__ float xw[3][4];
    int t = threadIdx.x;
    int lane = t & 63;
    int wid  = t >> 6;
    float bsum = 0.f, s0sum = 0.f, snegsum = 0.f;
    for (int b = 0; b < B; ++b) {
        float s = 0.f;
#pragma unroll
        for (int g = 0; g < NGRP; ++g)
            s += partial2[((size_t)b * NGRP + g) * NEG + t];
        float sneg = s * (1.0f / HW) * 0.5f;               // / HW / TEMPERATURE
        float l1m  = fmaxf(logf(1.0f - sneg), -100.0f);
        float ss = 0.f;
#pragma unroll
        for (int j = 0; j < HW / 256; ++j) {
            float n1 = n1map[b * HW + j * 256 + t];
            float n1sq = n1 * n1;
            ss += fminf(n1sq / fmaxf(n1sq, 1e-8f), 1.0f);
        }
        float r0 = sneg, r1 = l1m, r2 = ss;
#pragma unroll
        for (int o = 1; o < 64; o <<= 1) {
            r0 += __shfl_xor(r0, o);
            r1 += __shfl_xor(r1, o);
            r2 += __shfl_xor(r2, o);
        }
        if (lane == 0) { xw[0][wid] = r0; xw[1][wid] = r1; xw[2][wid] = r2; }
        __syncthreads();
        if (t == 0) {
            float sn = xw[0][0] + xw[0][1] + xw[0][2] + xw[0][3];
            float lm = xw[1][0] + xw[1][1] + xw[1][2] + xw[1][3];
            float sv = xw[2][0] + xw[2][1] + xw[2][2] + xw[2][3];
            float s0 = sv * (1.0f / HW);
            bsum    += -(fmaxf(logf(s0), -100.0f) + lm) * (1.0f / (NEG + 1));
            s0sum   += s0;
            snegsum += sn;
        }
        __syncthreads();
    }
    if (t == 0) {
        out[0] = bsum * 0.25f;                              // mean bce
        out[1] = s0sum * 0.25f;                             // sim_all[0] / B
        out[2] = snegsum * (1.0f / NEG) * 2.0f * 0.25f;     // sum/NEG*TEMP/B
    }
}

extern "C" void kernel_launch(void* const* d_in, const int* in_sizes, int n_in,
                              void* d_out, int out_size, void* d_ws, size_t ws_size,
                              hipStream_t stream) {
    const float* v1   = (const float*)d_in[0];
    const float* v2   = (const float*)d_in[1];
    const float* img  = (const float*)d_in[2];
    const int*   negh = (const int*)d_in[3];
    const int*   negw = (const int*)d_in[4];
    float* out = (float*)d_out;
    float* ws  = (float*)d_ws;

    uchar*  z2Ag     = (uchar*)(ws + OFF_Z2A);
    uchar*  z2Bg     = (uchar*)(ws + OFF_Z2B);
    float*  n1map    = ws + OFF_N1MAP;
    ushort* img_u16  = (ushort*)(ws + OFF_IMGU16);
    float*  partial2 = ws + OFF_PART2;

    hipLaunchKernelGGL(k_prep, dim3(320), dim3(256), 0, stream,
                       v2, v1, img, z2Ag, z2Bg, n1map, img_u16, partial2);
    hipLaunchKernelGGL(k_main, dim3(NBLK), dim3(1024), 0, stream,
                       v1, negh, negw, (const uint4*)z2Ag, (const uint4*)z2Bg,
                       n1map, img_u16, partial2);
    hipLaunchKernelGGL(k_reduce2f, dim3(1), dim3(256), 0, stream, partial2, n1map, out);
}

// Round 16
// 33.152 us; speedup vs baseline: 1.0336x; 1.0336x over previous
//
#include <hip/hip_runtime.h>
#include <math.h>

typedef unsigned short ushort;
typedef unsigned int uint;
typedef unsigned char uchar;

#define B 4
#define C 64
#define H 64
#define W 64
#define HW 4096
#define NEG 256
#define NGRP 16
#define PXB 64                   // pixels per k_main block
#define NBLK (B * HW / PXB)      // 256 blocks = 1 per CU

#define QS 7.49f
#define INVQS2 (1.0f / (QS * QS))
#define RGBNORM5 0.0186243f      // 1/(31*sqrt(3))

// ---------------- ws layout (float units) ----------------
// z2P    : [B][8][HW] uint planes (plane j = channels 8j..8j+7, int4 packed)
// n1map  : [B][HW]
// imgu16 : [HW] ushort RGB555
// partial2:[B][NGRP][NEG]  (atomically accumulated; zeroed by k_prep)
#define OFF_Z2P    0
#define OFF_N1MAP  (OFF_Z2P + B*HW*8)
#define OFF_IMGU16 (OFF_N1MAP + B*HW)
#define OFF_PART2  (OFF_IMGU16 + HW/2)

__device__ __forceinline__ int nib(uint u, int j) {
    return ((int)(u << (28 - 4 * j))) >> 28;
}
__device__ __forceinline__ int dot8(uint a, uint b, int c) {
#if __has_builtin(__builtin_amdgcn_sdot8)
    return __builtin_amdgcn_sdot8((int)a, (int)b, c, false);
#else
#pragma unroll
    for (int j = 0; j < 8; ++j) c += nib(a, j) * nib(b, j);
    return c;
#endif
}

// Combined prep: blocks [0,256) transpose+quantize z2 -> planar int4 planes;
// blocks [256,320) do n1map + RGB555 img table + zero partial2.
__global__ __launch_bounds__(256) void k_prep(const float* __restrict__ v2,
                                              const float* __restrict__ v1,
                                              const float* __restrict__ img,
                                              uint* __restrict__ z2P,
                                              float* __restrict__ n1map,
                                              ushort* __restrict__ img_u16,
                                              float* __restrict__ partial2) {
    int t = threadIdx.x;
    if (blockIdx.x < 256) {
        __shared__ float tile[64][65];
        __shared__ float npart[4][64];
        __shared__ float ninv[64];
        int b  = blockIdx.x >> 6;
        int q0 = (blockIdx.x & 63) * 64;
        int qq = t & 63;
        int cg = t >> 6;
        const float* src = v2 + (size_t)b * C * HW;
        float acc = 0.f;
#pragma unroll
        for (int r = 0; r < 16; ++r) {
            int c = cg * 16 + r;
            float v = src[(size_t)c * HW + q0 + qq];
            tile[c][qq] = v;
            acc += v * v;
        }
        npart[cg][qq] = acc;
        __syncthreads();
        if (t < 64) {
            float s = npart[0][t] + npart[1][t] + npart[2][t] + npart[3][t];
            ninv[t] = QS / fmaxf(sqrtf(s), 1e-8f);
        }
        __syncthreads();
        int qw   = t >> 2;
        int quad = t & 3;
        int c0   = quad * 16;
        float inv = ninv[qw];
        uint u0 = 0, u1 = 0;
#pragma unroll
        for (int j = 0; j < 8; ++j) {
            int x0 = (int)rintf(tile[c0 + j][qw] * inv);
            int x1 = (int)rintf(tile[c0 + 8 + j][qw] * inv);
            u0 |= (uint)(x0 & 0xF) << (4 * j);
            u1 |= (uint)(x1 & 0xF) << (4 * j);
        }
        size_t base = (size_t)b * 8 * HW;
        z2P[base + (size_t)(2 * quad)     * HW + q0 + qw] = u0;
        z2P[base + (size_t)(2 * quad + 1) * HW + q0 + qw] = u1;
    } else {
        int bid = blockIdx.x - 256;          // 0..63
        int b = bid >> 4;
        int q = (bid & 15) * 256 + t;
        partial2[bid * 256 + t] = 0.f;       // 64*256 == B*NGRP*NEG
        const float* src = v1 + (size_t)b * C * HW + q;
        float acc = 0.f;
#pragma unroll 8
        for (int c = 0; c < C; ++c) {
            float v = src[(size_t)c * HW];
            acc += v * v;
        }
        n1map[b * HW + q] = sqrtf(acc);
        if (b == 0) {
            uint r  = (uint)rintf(img[q] * 31.f);
            uint g  = (uint)rintf(img[HW + q] * 31.f);
            uint bl = (uint)rintf(img[2 * HW + q] * 31.f);
            img_u16[q] = (ushort)(r | (g << 5) | (bl << 10));
        }
    }
}

// Main: 256 blocks x 1024 threads (16 waves/CU). Whole-item z2 in LDS as 8 planar
// uint[HW] planes (gather bank = qv%32, uniform -> conflict-free); img table in LDS;
// thread = (k, px-quarter), 16 px each.
__global__ __launch_bounds__(1024) void k_main(const float* __restrict__ v1,
                                               const int* __restrict__ negh,
                                               const int* __restrict__ negw,
                                               const uint4* __restrict__ z2Pg,
                                               const float* __restrict__ n1map,
                                               const ushort* __restrict__ img_u16,
                                               float* __restrict__ partial2) {
    __shared__ uint z2p[8][HW];             // 128 KB: plane j = channels 8j..8j+7
    __shared__ ushort imgu[HW];             // 8 KB RGB555
    __shared__ uint z1q[PXB][8];            // 2 KB int4-packed z1 columns
    int b  = blockIdx.x >> 6;
    int p0 = (blockIdx.x & 63) * PXB;
    int t  = threadIdx.x;

    {   // stage whole-item z2 planes + img table, fully coalesced
        const uint4* gp = z2Pg + (size_t)b * 8 * (HW / 4);
        uint4* d4 = (uint4*)z2p;
#pragma unroll
        for (int i = 0; i < 8; ++i) d4[i * 1024 + t] = gp[i * 1024 + t];
        if (t < 512) ((uint4*)imgu)[t] = ((const uint4*)img_u16)[t];
    }
    if (t < 512) {   // stage z1 columns, normalized xQS -> int4 packed (64 px x 8)
        int px = t >> 3;
        int ui = t & 7;
        const float* srcb = v1 + (size_t)b * C * HW + p0 + px;
        float inv = QS / fmaxf(n1map[b * HW + p0 + px], 1e-8f);
        uint u = 0;
#pragma unroll
        for (int j = 0; j < 8; ++j) {
            int x = (int)rintf(srcb[(size_t)(8 * ui + j) * HW] * inv);
            u |= (uint)(x & 0xF) << (4 * j);
        }
        z1q[px][ui] = u;
    }
    __syncthreads();

    const float inv_max_euc = 1.0f / sqrtf((float)((H - 1) * (H - 1) + (W - 1) * (W - 1)));
    int k       = t & 255;
    int quarter = t >> 8;                  // 0..3
    int pbase   = p0 + quarter * 16;
    const int* nh = negh + ((size_t)b * HW + pbase) * NEG + k;
    const int* nw = negw + ((size_t)b * HW + pbase) * NEG + k;

    float acc = 0.f;
#pragma unroll 2
    for (int j0 = 0; j0 < 16; j0 += 8) {
        int ihv[8], iwv[8];
#pragma unroll
        for (int j = 0; j < 8; ++j) {
            ihv[j] = nh[(j0 + j) * NEG];
            iwv[j] = nw[(j0 + j) * NEG];
        }
#pragma unroll
        for (int j = 0; j < 8; ++j) {
            int px = quarter * 16 + j0 + j;
            int p  = pbase + j0 + j;
            int ih = ihv[j], iw = iwv[j];
            int qv = (ih << 6) + iw;
            // weight
            float dh = (float)(p >> 6) - (float)ih;
            float dw = (float)(p & 63) - (float)iw;
            float euc = sqrtf(dh * dh + dw * dw) * inv_max_euc;
            uint up = imgu[p];                 // wave-uniform -> broadcast
            uint uq = imgu[qv];                // scattered LDS u16 (2-way, free)
            int dr = (int)(up & 31u)         - (int)(uq & 31u);
            int dg = (int)((up >> 5) & 31u)  - (int)((uq >> 5) & 31u);
            int db = (int)((up >> 10) & 31u) - (int)((uq >> 10) & 31u);
            float rgb = sqrtf((float)(dr * dr + dg * dg + db * db)) * RGBNORM5;
            float wv = (0.8f * euc + 0.2f * rgb) * INVQS2;
            // gather from LDS: 8 planar b32 reads, bank = qv%32 -> conflict-free
            uint a0 = z2p[0][qv];
            uint a1 = z2p[1][qv];
            uint a2 = z2p[2][qv];
            uint a3 = z2p[3][qv];
            uint a4 = z2p[4][qv];
            uint a5 = z2p[5][qv];
            uint a6 = z2p[6][qv];
            uint a7 = z2p[7][qv];
            const uint4* zc = (const uint4*)(&z1q[px][0]);   // uniform -> broadcast
            uint4 u0 = zc[0];
            uint4 u1 = zc[1];
            int di = 0;
            di = dot8(a0, u0.x, di);
            di = dot8(a1, u0.y, di);
            di = dot8(a2, u0.z, di);
            di = dot8(a3, u0.w, di);
            di = dot8(a4, u1.x, di);
            di = dot8(a5, u1.y, di);
            di = dot8(a6, u1.z, di);
            di = dot8(a7, u1.w, di);
            acc += fminf(fabsf((float)di * wv), 1.0f);
        }
    }
    atomicAdd(&partial2[((size_t)b * NGRP + ((blockIdx.x & 63) >> 2)) * NEG + k], acc);
}

// Merged stage-2 + final with shfl wave reductions.
__global__ __launch_bounds__(256) void k_reduce2f(const float* __restrict__ partial2,
                                                  const float* __restrict__ n1map,
                                                  float* __restrict__ out) {
    __shared__ float xw[3][4];
    int t = threadIdx.x;
    int lane = t & 63;
    int wid  = t >> 6;
    float bsum = 0.f, s0sum = 0.f, snegsum = 0.f;
    for (int b = 0; b < B; ++b) {
        float s = 0.f;
#pragma unroll
        for (int g = 0; g < NGRP; ++g)
            s += partial2[((size_t)b * NGRP + g) * NEG + t];
        float sneg = s * (1.0f / HW) * 0.5f;               // / HW / TEMPERATURE
        float l1m  = fmaxf(logf(1.0f - sneg), -100.0f);
        float ss = 0.f;
#pragma unroll
        for (int j = 0; j < HW / 256; ++j) {
            float n1 = n1map[b * HW + j * 256 + t];
            float n1sq = n1 * n1;
            ss += fminf(n1sq / fmaxf(n1sq, 1e-8f), 1.0f);
        }
        float r0 = sneg, r1 = l1m, r2 = ss;
#pragma unroll
        for (int o = 1; o < 64; o <<= 1) {
            r0 += __shfl_xor(r0, o);
            r1 += __shfl_xor(r1, o);
            r2 += __shfl_xor(r2, o);
        }
        if (lane == 0) { xw[0][wid] = r0; xw[1][wid] = r1; xw[2][wid] = r2; }
        __syncthreads();
        if (t == 0) {
            float sn = xw[0][0] + xw[0][1] + xw[0][2] + xw[0][3];
            float lm = xw[1][0] + xw[1][1] + xw[1][2] + xw[1][3];
            float sv = xw[2][0] + xw[2][1] + xw[2][2] + xw[2][3];
            float s0 = sv * (1.0f / HW);
            bsum    += -(fmaxf(logf(s0), -100.0f) + lm) * (1.0f / (NEG + 1));
            s0sum   += s0;
            snegsum += sn;
        }
        __syncthreads();
    }
    if (t == 0) {
        out[0] = bsum * 0.25f;                              // mean bce
        out[1] = s0sum * 0.25f;                             // sim_all[0] / B
        out[2] = snegsum * (1.0f / NEG) * 2.0f * 0.25f;     // sum/NEG*TEMP/B
    }
}

extern "C" void kernel_launch(void* const* d_in, const int* in_sizes, int n_in,
                              void* d_out, int out_size, void* d_ws, size_t ws_size,
                              hipStream_t stream) {
    const float* v1   = (const float*)d_in[0];
    const float* v2   = (const float*)d_in[1];
    const float* img  = (const float*)d_in[2];
    const int*   negh = (const int*)d_in[3];
    const int*   negw = (const int*)d_in[4];
    float* out = (float*)d_out;
    float* ws  = (float*)d_ws;

    uint*   z2P      = (uint*)(ws + OFF_Z2P);
    float*  n1map    = ws + OFF_N1MAP;
    ushort* img_u16  = (ushort*)(ws + OFF_IMGU16);
    float*  partial2 = ws + OFF_PART2;

    hipLaunchKernelGGL(k_prep, dim3(320), dim3(256), 0, stream,
                       v2, v1, img, z2P, n1map, img_u16, partial2);
    hipLaunchKernelGGL(k_main, dim3(NBLK), dim3(1024), 0, stream,
                       v1, negh, negw, (const uint4*)z2P, n1map, img_u16, partial2);
    hipLaunchKernelGGL(k_reduce2f, dim3(1), dim3(256), 0, stream, partial2, n1map, out);
}